// Round 4
// baseline (274.017 us; speedup 1.0000x reference)
//
#include <hip/hip_runtime.h>

// AdvectionLayer: bilinear warp of image [B=8,C=4,H=1024,W=1024] by flow [B,2,H,W].
//
// R1: planar gather, 274 us. R2: fp32 interleaved ws, 145 us. R3: fp16 ws, ~150 us.
// R4: fused LDS fp16 tile+halo, 135 us; traffic near-minimal, occupancy 41%.
// R5: 512-thr blocks -> occ 77%, 114 us / 2.6 TB/s: latency wall below HBM.
// R6: 64x32 tile, amp 2.41x, float4 staging: 96 us / 3.25 TB/s. VGPR_Count=32!
//     Compiler minimized regs -> staging's 12 float4 loads serialized into ~3
//     dependent rounds; low per-wave MLP is the remaining latency wall
//     (HBM 41%, VALU 19%, occ 67% - nothing saturated).
// R7 (this): 64x64 tile / 1024 thr / 4 px-thr. Staged 88x88 = 61.9 KB LDS ->
//     2 blk/CU x 16 waves = 32 waves/CU cap (100%). Amp 2.41 -> 1.89x.
//     MLP staging: exactly 2 entries/thread, all 8 float4 loads issued into
//     named regs BEFORE any convert (1 round trip, not 3); 2nd entry clamped
//     (duplicate identical write, no divergence). Flow issued first so its
//     latency hides under staging. launch_bounds(1024,8) -> VGPR<=64.

#define BB 8
#define CC 4
#define HH 1024
#define WW 1024
#define HW (HH * WW)

#define TX 64     // tile width  (output px)
#define TY 64     // tile height (output px)
#define HXL 12    // left x halo; window [x0-12, x0+76) keeps 16B alignment
#define HYT 11    // top y halo;  window [y0-11, y0+77)
#define RW 88     // staged cols; valid rx in [0, 86]
#define RH 88     // staged rows; valid ry in [0, 86]
#define NQ (RW / 4)        // 22 float4-quads per staged row
#define NENT (RH * NQ)     // 1936 staging entries; threads own 2 each

typedef _Float16 h4 __attribute__((ext_vector_type(4)));  // one px, 4 ch, 8 B
typedef _Float16 h8 __attribute__((ext_vector_type(8)));  // px pair, 16 B

__global__ __launch_bounds__(1024, 8) void advect_fused_kernel(
    const float* __restrict__ image,
    const float* __restrict__ flow,
    float* __restrict__ out)
{
    __shared__ h4 lds[RH][RW];   // 88*88*8 = 61952 B -> 2 blocks/CU

    const int tid = threadIdx.x;
    const int x0 = blockIdx.x * TX;
    const int y0 = blockIdx.y * TY;
    const int b  = blockIdx.z;

    const float* img = image + (size_t)b * CC * HW;
    const float* flb = flow + (size_t)b * 2 * HW;

    const int tx  = tid & 63;
    const int x   = x0 + tx;
    const int ty0 = tid >> 6;          // 0..15; rows ty0 + 16k, k=0..3

    // ---- issue flow loads first (latency hides under staging + barrier) ----
    float pfx[4], pfy[4];
#pragma unroll
    for (int k = 0; k < 4; ++k) {
        const float* fl = flb + (size_t)(y0 + ty0 + (k << 4)) * WW + x;
        pfx[k] = __builtin_nontemporal_load(fl);
        pfy[k] = __builtin_nontemporal_load(fl + HW);
    }

    // ---- stage 88x88 halo region: 2 entries/thread, loads ALL issued first ----
    // Entry e -> staged row r = e/22, quad q = e%22 (4 px, aligned float4 per
    // channel plane). Border quads clamp to valid aligned addresses; cells a
    // gather can read always hold the genuine pixel (xl,yl pre-clamped), and
    // clamp-mangled cells are never addressed. Entry 1 is index-clamped: the
    // tail threads re-write entry NENT-1 with identical bytes (benign).
    const int e0 = tid;
    const int e1 = min(tid + 1024, NENT - 1);
    const int r0 = e0 / NQ, q0 = e0 - r0 * NQ;
    const int r1 = e1 / NQ, q1 = e1 - r1 * NQ;
    const int gy0 = min(max(y0 - HYT + r0, 0), HH - 1);
    const int gx0 = min(max(x0 - HXL + 4 * q0, 0), WW - 4);
    const int gy1 = min(max(y0 - HYT + r1, 0), HH - 1);
    const int gx1 = min(max(x0 - HXL + 4 * q1, 0), WW - 4);
    const float* p0 = img + (size_t)gy0 * WW + gx0;
    const float* p1 = img + (size_t)gy1 * WW + gx1;

    const float4 a0 = *reinterpret_cast<const float4*>(p0);
    const float4 a1 = *reinterpret_cast<const float4*>(p0 + HW);
    const float4 a2 = *reinterpret_cast<const float4*>(p0 + 2 * HW);
    const float4 a3 = *reinterpret_cast<const float4*>(p0 + 3 * HW);
    const float4 b0 = *reinterpret_cast<const float4*>(p1);
    const float4 b1 = *reinterpret_cast<const float4*>(p1 + HW);
    const float4 b2 = *reinterpret_cast<const float4*>(p1 + 2 * HW);
    const float4 b3 = *reinterpret_cast<const float4*>(p1 + 3 * HW);

    {
        h8 lo, hi;
        lo[0] = (_Float16)a0.x; lo[1] = (_Float16)a1.x;
        lo[2] = (_Float16)a2.x; lo[3] = (_Float16)a3.x;
        lo[4] = (_Float16)a0.y; lo[5] = (_Float16)a1.y;
        lo[6] = (_Float16)a2.y; lo[7] = (_Float16)a3.y;
        hi[0] = (_Float16)a0.z; hi[1] = (_Float16)a1.z;
        hi[2] = (_Float16)a2.z; hi[3] = (_Float16)a3.z;
        hi[4] = (_Float16)a0.w; hi[5] = (_Float16)a1.w;
        hi[6] = (_Float16)a2.w; hi[7] = (_Float16)a3.w;
        *(h8*)&lds[r0][4 * q0]     = lo;
        *(h8*)&lds[r0][4 * q0 + 2] = hi;
    }
    {
        h8 lo, hi;
        lo[0] = (_Float16)b0.x; lo[1] = (_Float16)b1.x;
        lo[2] = (_Float16)b2.x; lo[3] = (_Float16)b3.x;
        lo[4] = (_Float16)b0.y; lo[5] = (_Float16)b1.y;
        lo[6] = (_Float16)b2.y; lo[7] = (_Float16)b3.y;
        hi[0] = (_Float16)b0.z; hi[1] = (_Float16)b1.z;
        hi[2] = (_Float16)b2.z; hi[3] = (_Float16)b3.z;
        hi[4] = (_Float16)b0.w; hi[5] = (_Float16)b1.w;
        hi[6] = (_Float16)b2.w; hi[7] = (_Float16)b3.w;
        *(h8*)&lds[r1][4 * q1]     = lo;
        *(h8*)&lds[r1][4 * q1 + 2] = hi;
    }
    __syncthreads();

    const float sxs = (float)WW / (float)(WW - 1);
    const float sys = (float)HH / (float)(HH - 1);

    float* outb = out + (size_t)b * CC * HW;

#pragma unroll
    for (int k = 0; k < 4; ++k) {
        const int y = y0 + ty0 + (k << 4);
        const float fx = pfx[k];
        const float fy = pfy[k];

        float ix = ((float)x + fx) * sxs - 0.5f;
        float iy = ((float)y + fy) * sys - 0.5f;
        ix = fminf(fmaxf(ix, 0.0f), (float)(WW - 1));
        iy = fminf(fmaxf(iy, 0.0f), (float)(HH - 1));
        const int xl = min((int)ix, WW - 2);
        const int yl = min((int)iy, HH - 2);
        const float wx = ix - (float)xl;
        const float wy = iy - (float)yl;
        const float u0 = 1.0f - wx;
        const float v0 = 1.0f - wy;

        const int rx = xl - x0 + HXL;
        const int ry = yl - y0 + HYT;

        float o0, o1, o2, o3;
        if ((unsigned)rx <= (unsigned)(RW - 2) && (unsigned)ry <= (unsigned)(RH - 2)) {
            const h4 a00 = lds[ry][rx];
            const h4 a01 = lds[ry][rx + 1];
            const h4 a10 = lds[ry + 1][rx];
            const h4 a11 = lds[ry + 1][rx + 1];
            o0 = v0 * (u0 * (float)a00[0] + wx * (float)a01[0])
               + wy * (u0 * (float)a10[0] + wx * (float)a11[0]);
            o1 = v0 * (u0 * (float)a00[1] + wx * (float)a01[1])
               + wy * (u0 * (float)a10[1] + wx * (float)a11[1]);
            o2 = v0 * (u0 * (float)a00[2] + wx * (float)a01[2])
               + wy * (u0 * (float)a10[2] + wx * (float)a11[2]);
            o3 = v0 * (u0 * (float)a00[3] + wx * (float)a01[3])
               + wy * (u0 * (float)a10[3] + wx * (float)a11[3]);
        } else {
            // Gaussian-tail fallback (~3e-4 of px): exact planar fp32 gather
            const size_t o00 = (size_t)yl * WW + xl;
            float2 t, bt;
            const float* pp = img + o00;
            __builtin_memcpy(&t,  pp,      8);
            __builtin_memcpy(&bt, pp + WW, 8);
            o0 = v0 * (u0 * t.x + wx * t.y) + wy * (u0 * bt.x + wx * bt.y);
            pp += HW;
            __builtin_memcpy(&t,  pp,      8);
            __builtin_memcpy(&bt, pp + WW, 8);
            o1 = v0 * (u0 * t.x + wx * t.y) + wy * (u0 * bt.x + wx * bt.y);
            pp += HW;
            __builtin_memcpy(&t,  pp,      8);
            __builtin_memcpy(&bt, pp + WW, 8);
            o2 = v0 * (u0 * t.x + wx * t.y) + wy * (u0 * bt.x + wx * bt.y);
            pp += HW;
            __builtin_memcpy(&t,  pp,      8);
            __builtin_memcpy(&bt, pp + WW, 8);
            o3 = v0 * (u0 * t.x + wx * t.y) + wy * (u0 * bt.x + wx * bt.y);
        }

        const size_t op = (size_t)y * WW + x;
        __builtin_nontemporal_store(o0, &outb[op]);
        __builtin_nontemporal_store(o1, &outb[HW + op]);
        __builtin_nontemporal_store(o2, &outb[2 * (size_t)HW + op]);
        __builtin_nontemporal_store(o3, &outb[3 * (size_t)HW + op]);
    }
}

extern "C" void kernel_launch(void* const* d_in, const int* in_sizes, int n_in,
                              void* d_out, int out_size, void* d_ws, size_t ws_size,
                              hipStream_t stream) {
    const float* image = (const float*)d_in[0];
    const float* flow  = (const float*)d_in[1];
    float* out = (float*)d_out;

    dim3 grid(WW / TX, HH / TY, BB);
    advect_fused_kernel<<<grid, 1024, 0, stream>>>(image, flow, out);
}